// Round 6
// baseline (348.798 us; speedup 1.0000x reference)
//
#include <hip/hip_runtime.h>
#include <stdint.h>

typedef unsigned short u16;

#define D_MODEL 2048
#define HEADS 16
#define HDIM 128
#define SEQ 2048
#define BATCH 2
#define NROWS (BATCH*SEQ)          // 4096
#define QKV_N (D_MODEL + 2*HDIM)   // 2304

// softmax scale folded into wq/bq at prep: 1/sqrt(128) * log2(e)
#define SC2F 0.12751743f

typedef __attribute__((ext_vector_type(8))) short bf16x8;
typedef __attribute__((ext_vector_type(4))) float f32x4;

__device__ inline u16 f2bf(float f) {
  union { float f; uint32_t u; } v; v.f = f;
  uint32_t r = v.u + 0x7FFFu + ((v.u >> 16) & 1u);
  return (u16)(r >> 16);
}
__device__ inline u16 f2bf_fast(float f) {
  union { float f; uint32_t u; } v; v.f = f;
  return (u16)((v.u + 0x8000u) >> 16);
}

__device__ inline void gload_lds16(const void* g, void* l) {
  __builtin_amdgcn_global_load_lds(
      (const __attribute__((address_space(1))) unsigned int*)g,
      (__attribute__((address_space(3))) unsigned int*)l, 16, 0, 0);
}

// ---------------- fused prep: x cvt + all-weight transpose + bias pack ------
// grid: [0,1024) grid-stride cvt x ; [1024,9728) transpose ; 9728 bias
// wq (and bq) are PRE-SCALED by SC2F so attention scores feed exp2 directly.
__global__ void prep_all(const float* __restrict__ x, u16* __restrict__ xb,
                         const float* __restrict__ wq, const float* __restrict__ wk,
                         const float* __restrict__ wv, const float* __restrict__ wo,
                         u16* __restrict__ wqkvT, u16* __restrict__ woT,
                         const float* __restrict__ bq, const float* __restrict__ bk,
                         const float* __restrict__ bv, float* __restrict__ biasq) {
  const int bid = blockIdx.x, tid = threadIdx.x;
  if (bid < 1024) {
    const float4* xf = (const float4*)x;
    ushort4* xo = (ushort4*)xb;
    int i = bid * 256 + tid;
#pragma unroll
    for (int r = 0; r < 8; r++, i += 262144) {
      float4 f = xf[i];
      ushort4 u;
      u.x = f2bf(f.x); u.y = f2bf(f.y); u.z = f2bf(f.z); u.w = f2bf(f.w);
      xo[i] = u;
    }
  } else if (bid < 9728) {
    __shared__ float t[32][33];
    const int b2 = bid - 1024;
    const int n0v = (b2 % 136) * 32, k0 = (b2 / 136) * 32;
    const float* src; int N, n0, drow; u16* dst; float scl = 1.0f;
    if (n0v < 2048)      { src = wq; N = 2048; n0 = n0v;        dst = wqkvT; drow = n0v; scl = SC2F; }
    else if (n0v < 2176) { src = wk; N = 128;  n0 = n0v - 2048; dst = wqkvT; drow = n0v; }
    else if (n0v < 2304) { src = wv; N = 128;  n0 = n0v - 2176; dst = wqkvT; drow = n0v; }
    else                 { src = wo; N = 2048; n0 = n0v - 2304; dst = woT;   drow = n0v - 2304; }
    const int tx = tid & 31, ty = tid >> 5;
#pragma unroll
    for (int i = 0; i < 4; i++)
      t[ty + 8*i][tx] = src[(size_t)(k0 + ty + 8*i) * N + n0 + tx];
    __syncthreads();
#pragma unroll
    for (int i = 0; i < 4; i++)
      dst[(size_t)(drow + ty + 8*i) * D_MODEL + k0 + tx] = f2bf(t[tx][ty + 8*i] * scl);
  } else {
    for (int i = tid; i < QKV_N; i += 256)
      biasq[i] = (i < D_MODEL) ? bq[i] * SC2F
               : ((i < D_MODEL + HDIM) ? bk[i - D_MODEL] : bv[i - D_MODEL - HDIM]);
  }
}

// ---------------- bf16 GEMM, 256x256 tile, BK=64, XOR-swizzled LDS -----------
// Scale-up of the proven DB=true 128x128 structure (same sync: full double
// buffer, ONE barrier per iter; same chunk-XOR swizzle; same inverse-swizzled
// global_load_lds staging idiom). 8 waves (512 thr); wave tile 128x64
// (wm = (wave>>2)*128, wn = (wave&3)*64); acc = f32x4[8][4] = 128 VGPR.
// Staged bytes per MFMA halve vs 128^2 (128 B vs 256 B) -> staging-rate
// relief is the point (m93 ladder: bigger tile +51%).
#define BM2 256
#define BN2 256
#define BKK 64

__global__ __launch_bounds__(512, 2) void gemm256(
    const u16* __restrict__ A, const u16* __restrict__ BT,
    const float* __restrict__ bias,
    u16* __restrict__ Cb, float* __restrict__ Cf,
    u16* __restrict__ vT,
    int M, int N, int tilesN, int K) {
  __shared__ __align__(16) u16 sA[2][BM2 * BKK];   // 32 KB each
  __shared__ __align__(16) u16 sB[2][BN2 * BKK];   // 32 KB each  (128 KB total)
  const int tid = threadIdx.x;
  const int wave = tid >> 6, lane = tid & 63;
  const int bm = blockIdx.x / tilesN, bn = blockIdx.x % tilesN;
  const int m0 = bm * BM2, n0 = bn * BN2;
  const int wm = (wave >> 2) * 128, wn = (wave & 3) * 64;
  const int l16 = lane & 15, quad = lane >> 4;

  f32x4 acc[8][4] = {};

  // DMA map: wave-op i (0..31) covers rows i*8 + (lane>>3);
  // global chunk = (lane&7)^(lane>>3)  (row&7 == lane>>3 since i*8 ≡ 0 mod 8)
  const int dRow = lane >> 3;
  const int dCol = ((lane & 7) ^ (lane >> 3)) * 8;

#define GDMA2(i, buf)                                                          \
  {                                                                            \
    const int _k0 = (i) * BKK;                                                 \
    _Pragma("unroll") for (int c = 0; c < 4; c++) {                            \
      const int op = wave * 4 + c;                                             \
      const int row = op * 8 + dRow;                                           \
      gload_lds16(&A[(size_t)(m0 + row) * K + _k0 + dCol], &sA[buf][op * 512]);\
      gload_lds16(&BT[(size_t)(n0 + row) * K + _k0 + dCol], &sB[buf][op * 512]);\
    }                                                                          \
  }

  const int NI = K / BKK;
  GDMA2(0, 0);
  for (int i = 0; i < NI; i++) {
    const int cur = i & 1;
    __syncthreads();                       // drains GDMA2(i); frees cur^1
    if (i + 1 < NI) GDMA2(i + 1, cur ^ 1);
#pragma unroll
    for (int kk2 = 0; kk2 < 2; kk2++) {    // K halves: kk = kk2*32
      bf16x8 bfr[4];
#pragma unroll
      for (int nb = 0; nb < 4; ++nb) {
        const int R = wn + nb * 16 + l16;
        const int s = (kk2 * 4 + quad) ^ (l16 & 7);
        bfr[nb] = *(const bf16x8*)&sB[cur][R * BKK + s * 8];
      }
#pragma unroll
      for (int mb = 0; mb < 8; ++mb) {
        const int R = wm + mb * 16 + l16;
        const int s = (kk2 * 4 + quad) ^ (l16 & 7);
        bf16x8 af = *(const bf16x8*)&sA[cur][R * BKK + s * 8];
#pragma unroll
        for (int nb = 0; nb < 4; ++nb)
          acc[mb][nb] = __builtin_amdgcn_mfma_f32_16x16x32_bf16(af, bfr[nb], acc[mb][nb], 0, 0, 0);
      }
    }
  }
#undef GDMA2

  // epilogue: C/D layout col=lane&15, row=(lane>>4)*4+r
#pragma unroll
  for (int mb = 0; mb < 8; ++mb) {
#pragma unroll
    for (int nb = 0; nb < 4; ++nb) {
      const int gn = n0 + wn + nb * 16 + l16;
      const float bb = bias ? bias[gn] : 0.0f;
#pragma unroll
      for (int r = 0; r < 4; ++r) {
        const int gm = m0 + wm + mb * 16 + quad * 4 + r;
        const float v = acc[mb][nb][r] + bb;
        if (Cf) {
          Cf[(size_t)gm * N + gn] = v;
        } else {
          const u16 u = f2bf(v);
          Cb[(size_t)gm * N + gn] = u;
          if (vT && gn >= D_MODEL + HDIM) {
            const int bi = gm >> 11, si = gm & 2047;
            vT[((size_t)bi * HDIM + (gn - D_MODEL - HDIM)) * SEQ + si] = u;
          }
        }
      }
    }
  }
}

// ---------------- flash-style MQA attention (FROZEN: R0-baseline struct) ----
// 4 waves x 32 q-rows, sK dbuf + sV single + sP wave-private, 2 barriers/iter,
// no setprio (R1 A/B: -2%). Only delta vs the 90.0 µs baseline: Q pre-scaled
// at prep (SC2F fold) so exp2 consumes scores directly.
__global__ __launch_bounds__(256) void mqa_attn(
    const u16* __restrict__ qkv, const u16* __restrict__ vT, u16* __restrict__ ctx) {
  __shared__ __align__(16) u16 sK[2][64 * 128];
  __shared__ __align__(16) u16 sV[128 * 64];
  __shared__ __align__(16) u16 sP[4][32 * 64];
  const int tid = threadIdx.x, wave = tid >> 6, lane = tid & 63;
  const int qt = blockIdx.x & 15;
  const int h  = (blockIdx.x >> 4) & 15;
  const int b  = blockIdx.x >> 8;
  const int bS = b * SEQ;
  const int q0 = qt * 128 + wave * 32;
  const int l16 = lane & 15, quad = lane >> 4;
  const int sw = l16 & 7;
  u16* myP = &sP[wave][0];

  bf16x8 qf[2][4];
#pragma unroll
  for (int mb = 0; mb < 2; mb++)
#pragma unroll
    for (int kc = 0; kc < 4; kc++)
      qf[mb][kc] = *(const bf16x8*)&qkv[(size_t)(bS + q0 + mb*16 + l16) * QKV_N
                                        + h*HDIM + kc*32 + quad*8];

  f32x4 o[2][8] = {};
  float lrow[2] = {0.f, 0.f};

  const u16* Kbase = qkv + (size_t)bS * QKV_N + D_MODEL;
  const u16* Vbase = vT + (size_t)b * HDIM * SEQ;

  const int kRowIn = lane >> 4;
  const int kChS   = lane & 15;
  const int vRowIn = lane >> 3;
  const int vChL   = (lane & 7) ^ (lane >> 3);

#define DMA_K(t, dst)                                                          \
  {                                                                            \
    const int _sk = (t) * 64;                                                  \
    _Pragma("unroll") for (int j = 0; j < 4; j++) {                            \
      const int i = wave * 4 + j;                                              \
      const int krow = i * 4 + kRowIn;                                         \
      const int kcl = kChS ^ (krow & 15);                                      \
      gload_lds16(&Kbase[(size_t)(_sk + krow) * QKV_N + kcl * 8],              \
                  &(dst)[i * 512]);                                            \
    }                                                                          \
  }
#define DMA_V(t)                                                               \
  {                                                                            \
    const int _sk = (t) * 64;                                                  \
    _Pragma("unroll") for (int j = 0; j < 4; j++) {                            \
      const int i = wave * 4 + j;                                              \
      const int d = i * 8 + vRowIn;                                            \
      gload_lds16(&Vbase[(size_t)d * SEQ + _sk + vChL * 8], &sV[i * 512]);     \
    }                                                                          \
  }

  DMA_K(0, sK[0]);
  DMA_V(0);
  __syncthreads();

  const int T = SEQ / 64;
  for (int t = 0; t < T; ++t) {
    const int cur = t & 1;
    if (t + 1 < T) DMA_K(t + 1, sK[cur ^ 1]);

    f32x4 sc[2][4];
#pragma unroll
    for (int nb = 0; nb < 4; nb++) {
      bf16x8 kf[4];
#pragma unroll
      for (int kc = 0; kc < 4; kc++)
        kf[kc] = *(const bf16x8*)&sK[cur][(nb*16 + l16) * 128 + (((kc*4 + quad) ^ l16) * 8)];
#pragma unroll
      for (int mb = 0; mb < 2; mb++) {
        f32x4 a = {0.f, 0.f, 0.f, 0.f};
#pragma unroll
        for (int kc = 0; kc < 4; kc++)
          a = __builtin_amdgcn_mfma_f32_16x16x32_bf16(kf[kc], qf[mb][kc], a, 0, 0, 0);
        sc[mb][nb] = a;
      }
    }

#pragma unroll
    for (int mb = 0; mb < 2; mb++)
#pragma unroll
      for (int nb = 0; nb < 4; nb++) {
        float p0 = __builtin_amdgcn_exp2f(sc[mb][nb][0]);
        float p1 = __builtin_amdgcn_exp2f(sc[mb][nb][1]);
        float p2 = __builtin_amdgcn_exp2f(sc[mb][nb][2]);
        float p3 = __builtin_amdgcn_exp2f(sc[mb][nb][3]);
        lrow[mb] += (p0 + p1) + (p2 + p3);
        uint32_t lo = (uint32_t)f2bf_fast(p0) | ((uint32_t)f2bf_fast(p1) << 16);
        uint32_t hi = (uint32_t)f2bf_fast(p2) | ((uint32_t)f2bf_fast(p3) << 16);
        uint2 w; w.x = lo; w.y = hi;
        const int pr = (nb*2 + (quad >> 1)) ^ sw;
        *(uint2*)&myP[(mb*16 + l16) * 64 + pr * 8 + (quad & 1) * 4] = w;
      }

    __syncthreads();

    bf16x8 pf[2][2];
#pragma unroll
    for (int mb = 0; mb < 2; mb++)
#pragma unroll
      for (int kc = 0; kc < 2; kc++)
        pf[mb][kc] = *(const bf16x8*)&myP[(mb*16 + l16) * 64 + (((kc*4 + quad) ^ sw) * 8)];

#pragma unroll
    for (int nb = 0; nb < 8; nb++) {
      bf16x8 vf[2];
#pragma unroll
      for (int kc = 0; kc < 2; kc++)
        vf[kc] = *(const bf16x8*)&sV[(nb*16 + l16) * 64 + (((kc*4 + quad) ^ (l16 & 7)) * 8)];
#pragma unroll
      for (int mb = 0; mb < 2; mb++)
#pragma unroll
        for (int kc = 0; kc < 2; kc++)
          o[mb][nb] = __builtin_amdgcn_mfma_f32_16x16x32_bf16(pf[mb][kc], vf[kc], o[mb][nb], 0, 0, 0);
    }

    __syncthreads();
    if (t + 1 < T) DMA_V(t + 1);
  }

#pragma unroll
  for (int mb = 0; mb < 2; mb++) {
    lrow[mb] += __shfl_xor(lrow[mb], 16, 64);
    lrow[mb] += __shfl_xor(lrow[mb], 32, 64);
  }
  float invl[2][4];
#pragma unroll
  for (int mb = 0; mb < 2; mb++)
#pragma unroll
    for (int r = 0; r < 4; r++)
      invl[mb][r] = 1.0f / __shfl(lrow[mb], quad * 4 + r, 64);

#pragma unroll
  for (int mb = 0; mb < 2; mb++)
#pragma unroll
    for (int nb = 0; nb < 8; nb++)
#pragma unroll
      for (int r = 0; r < 4; r++) {
        const int gq = q0 + mb*16 + quad*4 + r;
        const int gd = h * HDIM + nb*16 + l16;
        ctx[(size_t)(bS + gq) * D_MODEL + gd] = f2bf(o[mb][nb][r] * invl[mb][r]);
      }
}

// ---------------- launch ----------------
extern "C" void kernel_launch(void* const* d_in, const int* in_sizes, int n_in,
                              void* d_out, int out_size, void* d_ws, size_t ws_size,
                              hipStream_t stream) {
  const float* x  = (const float*)d_in[0];
  const float* wq = (const float*)d_in[1];
  const float* bq = (const float*)d_in[2];
  const float* wk = (const float*)d_in[3];
  const float* bk = (const float*)d_in[4];
  const float* wv = (const float*)d_in[5];
  const float* bv = (const float*)d_in[6];
  const float* wo = (const float*)d_in[7];
  const float* bo = (const float*)d_in[8];
  float* out = (float*)d_out;
  char* ws = (char*)d_ws;

  u16*   xb    = (u16*)(ws + 0);          // [4096,2048] bf16
  u16*   wqkvT = (u16*)(ws + 16777216);   // [2304,2048] bf16
  u16*   woT   = (u16*)(ws + 26214400);   // [2048,2048] bf16
  u16*   qkv   = (u16*)(ws + 34603008);   // [4096,2304] bf16
  u16*   vT    = (u16*)(ws + 53477376);   // [2,128,2048] bf16
  u16*   ctx   = (u16*)(ws + 54525952);   // [4096,2048] bf16
  float* biasq = (float*)(ws + 71303168); // [2304] f32

  prep_all<<<9729, 256, 0, stream>>>(x, xb, wq, wk, wv, wo, wqkvT, woT,
                                     bq, bk, bv, biasq);
  // merged QKV projection: 256^2 tiles, 16x9 = 144 blocks
  gemm256<<<16 * 9, 512, 0, stream>>>(xb, wqkvT, biasq, qkv, nullptr, vT,
                                      NROWS, QKV_N, 9, D_MODEL);
  // attention: frozen R0-baseline structure
  mqa_attn<<<BATCH * HEADS * (SEQ / 128), 256, 0, stream>>>(qkv, vT, ctx);
  // output projection: 256^2 tiles, 16x8 = 128 blocks
  gemm256<<<16 * 8, 512, 0, stream>>>(ctx, woT, bo, nullptr, out, nullptr,
                                      NROWS, D_MODEL, 8, D_MODEL);
}

// Round 7
// 292.647 us; speedup vs baseline: 1.1919x; 1.1919x over previous
//
#include <hip/hip_runtime.h>
#include <stdint.h>

typedef unsigned short u16;

#define D_MODEL 2048
#define HEADS 16
#define HDIM 128
#define SEQ 2048
#define BATCH 2
#define NROWS (BATCH*SEQ)          // 4096
#define QKV_N (D_MODEL + 2*HDIM)   // 2304

// softmax scale folded into wq/bq at prep: 1/sqrt(128) * log2(e)
#define SC2F 0.12751743f

typedef __attribute__((ext_vector_type(8))) short bf16x8;
typedef __attribute__((ext_vector_type(4))) float f32x4;

__device__ inline u16 f2bf(float f) {
  union { float f; uint32_t u; } v; v.f = f;
  uint32_t r = v.u + 0x7FFFu + ((v.u >> 16) & 1u);
  return (u16)(r >> 16);
}
__device__ inline u16 f2bf_fast(float f) {
  union { float f; uint32_t u; } v; v.f = f;
  return (u16)((v.u + 0x8000u) >> 16);
}

__device__ inline void gload_lds16(const void* g, void* l) {
  __builtin_amdgcn_global_load_lds(
      (const __attribute__((address_space(1))) unsigned int*)g,
      (__attribute__((address_space(3))) unsigned int*)l, 16, 0, 0);
}

// ---------------- fused prep: x cvt + all-weight transpose + bias pack ------
// grid: [0,1024) grid-stride cvt x ; [1024,9728) transpose ; 9728 bias
// wq (and bq) are PRE-SCALED by SC2F so attention scores feed exp2 directly.
__global__ void prep_all(const float* __restrict__ x, u16* __restrict__ xb,
                         const float* __restrict__ wq, const float* __restrict__ wk,
                         const float* __restrict__ wv, const float* __restrict__ wo,
                         u16* __restrict__ wqkvT, u16* __restrict__ woT,
                         const float* __restrict__ bq, const float* __restrict__ bk,
                         const float* __restrict__ bv, float* __restrict__ biasq) {
  const int bid = blockIdx.x, tid = threadIdx.x;
  if (bid < 1024) {
    const float4* xf = (const float4*)x;
    ushort4* xo = (ushort4*)xb;
    int i = bid * 256 + tid;
#pragma unroll
    for (int r = 0; r < 8; r++, i += 262144) {
      float4 f = xf[i];
      ushort4 u;
      u.x = f2bf(f.x); u.y = f2bf(f.y); u.z = f2bf(f.z); u.w = f2bf(f.w);
      xo[i] = u;
    }
  } else if (bid < 9728) {
    __shared__ float t[32][33];
    const int b2 = bid - 1024;
    const int n0v = (b2 % 136) * 32, k0 = (b2 / 136) * 32;
    const float* src; int N, n0, drow; u16* dst; float scl = 1.0f;
    if (n0v < 2048)      { src = wq; N = 2048; n0 = n0v;        dst = wqkvT; drow = n0v; scl = SC2F; }
    else if (n0v < 2176) { src = wk; N = 128;  n0 = n0v - 2048; dst = wqkvT; drow = n0v; }
    else if (n0v < 2304) { src = wv; N = 128;  n0 = n0v - 2176; dst = wqkvT; drow = n0v; }
    else                 { src = wo; N = 2048; n0 = n0v - 2304; dst = woT;   drow = n0v - 2304; }
    const int tx = tid & 31, ty = tid >> 5;
#pragma unroll
    for (int i = 0; i < 4; i++)
      t[ty + 8*i][tx] = src[(size_t)(k0 + ty + 8*i) * N + n0 + tx];
    __syncthreads();
#pragma unroll
    for (int i = 0; i < 4; i++)
      dst[(size_t)(drow + ty + 8*i) * D_MODEL + k0 + tx] = f2bf(t[tx][ty + 8*i] * scl);
  } else {
    for (int i = tid; i < QKV_N; i += 256)
      biasq[i] = (i < D_MODEL) ? bq[i] * SC2F
               : ((i < D_MODEL + HDIM) ? bk[i - D_MODEL] : bv[i - D_MODEL - HDIM]);
  }
}

// ---------------- bf16 GEMM, BK=64, XOR-swizzled LDS (proven 128x128) --------
// C = A[M,K]*BT[N,K]^T + bias. 128x128 tile, 4 waves (64x64 each).
// DB=false: single-buffered (32 KB), 2 barriers/iter; MINW=3 hints 3 waves/EU
//           (VGPR <= ~168) so up to 3 blocks/CU co-reside on the 576-block grid.
// DB=true : double-buffered (64 KB), 1 barrier/iter; LDS-capped at 2 blocks/CU,
//           MINW=2 leaves the allocator loose.
#define BM 128
#define BN 128
#define BKK 64

template <bool DB, int MINW>
__global__ __launch_bounds__(256, MINW) void gemm_bt(
    const u16* __restrict__ A, const u16* __restrict__ BT,
    const float* __restrict__ bias,
    u16* __restrict__ Cb, float* __restrict__ Cf,
    u16* __restrict__ vT,
    int M, int N, int tilesN, int K) {
  __shared__ __align__(16) u16 sA[DB ? 2 : 1][BM * BKK];   // 16 KB each
  __shared__ __align__(16) u16 sB[DB ? 2 : 1][BN * BKK];
  const int tid = threadIdx.x;
  const int wave = tid >> 6, lane = tid & 63;
  const int bm = blockIdx.x / tilesN, bn = blockIdx.x % tilesN;
  const int m0 = bm * BM, n0 = bn * BN;
  const int wm = (wave & 1) * 64, wn = (wave >> 1) * 64;
  const int l16 = lane & 15, quad = lane >> 4;

  f32x4 acc[4][4] = {};

  // DMA map: op i (0..15) covers rows i*8 + (lane>>3); global chunk = (lane&7)^(lane>>3)
  const int dRow = lane >> 3;
  const int dCol = ((lane & 7) ^ (lane >> 3)) * 8;

#define GDMA(i, buf)                                                           \
  {                                                                            \
    const int _k0 = (i) * BKK;                                                 \
    _Pragma("unroll") for (int c = 0; c < 4; c++) {                            \
      const int op = wave * 4 + c;                                             \
      const int row = op * 8 + dRow;                                           \
      gload_lds16(&A[(size_t)(m0 + row) * K + _k0 + dCol], &sA[buf][op * 512]);\
      gload_lds16(&BT[(size_t)(n0 + row) * K + _k0 + dCol], &sB[buf][op * 512]);\
    }                                                                          \
  }

  const int NI = K / BKK;
  GDMA(0, 0);
  for (int i = 0; i < NI; i++) {
    const int cur = DB ? (i & 1) : 0;
    __syncthreads();                       // drain DMA(i)
    if (DB && i + 1 < NI) GDMA(i + 1, cur ^ 1);
#pragma unroll
    for (int kk2 = 0; kk2 < 2; kk2++) {    // K halves: kk = kk2*32
      bf16x8 af[4], bfr[4];
#pragma unroll
      for (int mb = 0; mb < 4; ++mb) {
        const int R = wm + mb * 16 + l16;
        const int s = (kk2 * 4 + quad) ^ (l16 & 7);
        af[mb] = *(const bf16x8*)&sA[cur][R * BKK + s * 8];
      }
#pragma unroll
      for (int nb = 0; nb < 4; ++nb) {
        const int R = wn + nb * 16 + l16;
        const int s = (kk2 * 4 + quad) ^ (l16 & 7);
        bfr[nb] = *(const bf16x8*)&sB[cur][R * BKK + s * 8];
      }
#pragma unroll
      for (int mb = 0; mb < 4; ++mb)
#pragma unroll
        for (int nb = 0; nb < 4; ++nb)
          acc[mb][nb] = __builtin_amdgcn_mfma_f32_16x16x32_bf16(af[mb], bfr[nb], acc[mb][nb], 0, 0, 0);
    }
    if (!DB) {
      __syncthreads();                     // all readers done with the buffer
      if (i + 1 < NI) GDMA(i + 1, 0);
    }
  }
#undef GDMA

  // epilogue: C/D layout col=lane&15, row=(lane>>4)*4+r
#pragma unroll
  for (int mb = 0; mb < 4; ++mb) {
#pragma unroll
    for (int nb = 0; nb < 4; ++nb) {
      const int gn = n0 + wn + nb * 16 + l16;
      const float bb = bias ? bias[gn] : 0.0f;
#pragma unroll
      for (int r = 0; r < 4; ++r) {
        const int gm = m0 + wm + mb * 16 + quad * 4 + r;
        const float v = acc[mb][nb][r] + bb;
        if (Cf) {
          Cf[(size_t)gm * N + gn] = v;
        } else {
          const u16 u = f2bf(v);
          Cb[(size_t)gm * N + gn] = u;
          if (vT && gn >= D_MODEL + HDIM) {
            const int bi = gm >> 11, si = gm & 2047;
            vT[((size_t)bi * HDIM + (gn - D_MODEL - HDIM)) * SEQ + si] = u;
          }
        }
      }
    }
  }
}

// ---------------- flash-style MQA attention (FROZEN: R0-baseline struct) ----
// 4 waves x 32 q-rows, sK dbuf + sV single + sP wave-private, 2 barriers/iter,
// no setprio (R1 A/B: -2%). Q pre-scaled at prep (SC2F) -> exp2 direct.
// Measured 86.4 µs in R5 — best attn config of the session.
__global__ __launch_bounds__(256) void mqa_attn(
    const u16* __restrict__ qkv, const u16* __restrict__ vT, u16* __restrict__ ctx) {
  __shared__ __align__(16) u16 sK[2][64 * 128];
  __shared__ __align__(16) u16 sV[128 * 64];
  __shared__ __align__(16) u16 sP[4][32 * 64];
  const int tid = threadIdx.x, wave = tid >> 6, lane = tid & 63;
  const int qt = blockIdx.x & 15;
  const int h  = (blockIdx.x >> 4) & 15;
  const int b  = blockIdx.x >> 8;
  const int bS = b * SEQ;
  const int q0 = qt * 128 + wave * 32;
  const int l16 = lane & 15, quad = lane >> 4;
  const int sw = l16 & 7;
  u16* myP = &sP[wave][0];

  bf16x8 qf[2][4];
#pragma unroll
  for (int mb = 0; mb < 2; mb++)
#pragma unroll
    for (int kc = 0; kc < 4; kc++)
      qf[mb][kc] = *(const bf16x8*)&qkv[(size_t)(bS + q0 + mb*16 + l16) * QKV_N
                                        + h*HDIM + kc*32 + quad*8];

  f32x4 o[2][8] = {};
  float lrow[2] = {0.f, 0.f};

  const u16* Kbase = qkv + (size_t)bS * QKV_N + D_MODEL;
  const u16* Vbase = vT + (size_t)b * HDIM * SEQ;

  const int kRowIn = lane >> 4;
  const int kChS   = lane & 15;
  const int vRowIn = lane >> 3;
  const int vChL   = (lane & 7) ^ (lane >> 3);

#define DMA_K(t, dst)                                                          \
  {                                                                            \
    const int _sk = (t) * 64;                                                  \
    _Pragma("unroll") for (int j = 0; j < 4; j++) {                            \
      const int i = wave * 4 + j;                                              \
      const int krow = i * 4 + kRowIn;                                         \
      const int kcl = kChS ^ (krow & 15);                                      \
      gload_lds16(&Kbase[(size_t)(_sk + krow) * QKV_N + kcl * 8],              \
                  &(dst)[i * 512]);                                            \
    }                                                                          \
  }
#define DMA_V(t)                                                               \
  {                                                                            \
    const int _sk = (t) * 64;                                                  \
    _Pragma("unroll") for (int j = 0; j < 4; j++) {                            \
      const int i = wave * 4 + j;                                              \
      const int d = i * 8 + vRowIn;                                            \
      gload_lds16(&Vbase[(size_t)d * SEQ + _sk + vChL * 8], &sV[i * 512]);     \
    }                                                                          \
  }

  DMA_K(0, sK[0]);
  DMA_V(0);
  __syncthreads();

  const int T = SEQ / 64;
  for (int t = 0; t < T; ++t) {
    const int cur = t & 1;
    if (t + 1 < T) DMA_K(t + 1, sK[cur ^ 1]);

    f32x4 sc[2][4];
#pragma unroll
    for (int nb = 0; nb < 4; nb++) {
      bf16x8 kf[4];
#pragma unroll
      for (int kc = 0; kc < 4; kc++)
        kf[kc] = *(const bf16x8*)&sK[cur][(nb*16 + l16) * 128 + (((kc*4 + quad) ^ l16) * 8)];
#pragma unroll
      for (int mb = 0; mb < 2; mb++) {
        f32x4 a = {0.f, 0.f, 0.f, 0.f};
#pragma unroll
        for (int kc = 0; kc < 4; kc++)
          a = __builtin_amdgcn_mfma_f32_16x16x32_bf16(kf[kc], qf[mb][kc], a, 0, 0, 0);
        sc[mb][nb] = a;
      }
    }

#pragma unroll
    for (int mb = 0; mb < 2; mb++)
#pragma unroll
      for (int nb = 0; nb < 4; nb++) {
        float p0 = __builtin_amdgcn_exp2f(sc[mb][nb][0]);
        float p1 = __builtin_amdgcn_exp2f(sc[mb][nb][1]);
        float p2 = __builtin_amdgcn_exp2f(sc[mb][nb][2]);
        float p3 = __builtin_amdgcn_exp2f(sc[mb][nb][3]);
        lrow[mb] += (p0 + p1) + (p2 + p3);
        uint32_t lo = (uint32_t)f2bf_fast(p0) | ((uint32_t)f2bf_fast(p1) << 16);
        uint32_t hi = (uint32_t)f2bf_fast(p2) | ((uint32_t)f2bf_fast(p3) << 16);
        uint2 w; w.x = lo; w.y = hi;
        const int pr = (nb*2 + (quad >> 1)) ^ sw;
        *(uint2*)&myP[(mb*16 + l16) * 64 + pr * 8 + (quad & 1) * 4] = w;
      }

    __syncthreads();

    bf16x8 pf[2][2];
#pragma unroll
    for (int mb = 0; mb < 2; mb++)
#pragma unroll
      for (int kc = 0; kc < 2; kc++)
        pf[mb][kc] = *(const bf16x8*)&myP[(mb*16 + l16) * 64 + (((kc*4 + quad) ^ sw) * 8)];

#pragma unroll
    for (int nb = 0; nb < 8; nb++) {
      bf16x8 vf[2];
#pragma unroll
      for (int kc = 0; kc < 2; kc++)
        vf[kc] = *(const bf16x8*)&sV[(nb*16 + l16) * 64 + (((kc*4 + quad) ^ (l16 & 7)) * 8)];
#pragma unroll
      for (int mb = 0; mb < 2; mb++)
#pragma unroll
        for (int kc = 0; kc < 2; kc++)
          o[mb][nb] = __builtin_amdgcn_mfma_f32_16x16x32_bf16(pf[mb][kc], vf[kc], o[mb][nb], 0, 0, 0);
    }

    __syncthreads();
    if (t + 1 < T) DMA_V(t + 1);
  }

#pragma unroll
  for (int mb = 0; mb < 2; mb++) {
    lrow[mb] += __shfl_xor(lrow[mb], 16, 64);
    lrow[mb] += __shfl_xor(lrow[mb], 32, 64);
  }
  float invl[2][4];
#pragma unroll
  for (int mb = 0; mb < 2; mb++)
#pragma unroll
    for (int r = 0; r < 4; r++)
      invl[mb][r] = 1.0f / __shfl(lrow[mb], quad * 4 + r, 64);

#pragma unroll
  for (int mb = 0; mb < 2; mb++)
#pragma unroll
    for (int nb = 0; nb < 8; nb++)
#pragma unroll
      for (int r = 0; r < 4; r++) {
        const int gq = q0 + mb*16 + quad*4 + r;
        const int gd = h * HDIM + nb*16 + l16;
        ctx[(size_t)(bS + gq) * D_MODEL + gd] = f2bf(o[mb][nb][r] * invl[mb][r]);
      }
}

// ---------------- launch ----------------
extern "C" void kernel_launch(void* const* d_in, const int* in_sizes, int n_in,
                              void* d_out, int out_size, void* d_ws, size_t ws_size,
                              hipStream_t stream) {
  const float* x  = (const float*)d_in[0];
  const float* wq = (const float*)d_in[1];
  const float* bq = (const float*)d_in[2];
  const float* wk = (const float*)d_in[3];
  const float* bk = (const float*)d_in[4];
  const float* wv = (const float*)d_in[5];
  const float* bv = (const float*)d_in[6];
  const float* wo = (const float*)d_in[7];
  const float* bo = (const float*)d_in[8];
  float* out = (float*)d_out;
  char* ws = (char*)d_ws;

  u16*   xb    = (u16*)(ws + 0);          // [4096,2048] bf16
  u16*   wqkvT = (u16*)(ws + 16777216);   // [2304,2048] bf16
  u16*   woT   = (u16*)(ws + 26214400);   // [2048,2048] bf16
  u16*   qkv   = (u16*)(ws + 34603008);   // [4096,2304] bf16
  u16*   vT    = (u16*)(ws + 53477376);   // [2,128,2048] bf16
  u16*   ctx   = (u16*)(ws + 54525952);   // [4096,2048] bf16
  float* biasq = (float*)(ws + 71303168); // [2304] f32

  prep_all<<<9729, 256, 0, stream>>>(x, xb, wq, wk, wv, wo, wqkvT, woT,
                                     bq, bk, bv, biasq);
  // merged QKV projection: 576 blocks, single-buffered, 3-waves/EU hint
  gemm_bt<false, 3><<<32 * 18, 256, 0, stream>>>(xb, wqkvT, biasq, qkv, nullptr, vT,
                                                 NROWS, QKV_N, 18, D_MODEL);
  // attention: frozen best config (R5, 86.4 µs)
  mqa_attn<<<BATCH * HEADS * (SEQ / 128), 256, 0, stream>>>(qkv, vT, ctx);
  // output projection: 512 blocks (2/CU), double-buffered
  gemm_bt<true, 2><<<32 * 16, 256, 0, stream>>>(ctx, woT, bo, nullptr, out, nullptr,
                                                NROWS, D_MODEL, 16, D_MODEL);
}

// Round 8
// 290.974 us; speedup vs baseline: 1.1987x; 1.0057x over previous
//
#include <hip/hip_runtime.h>
#include <stdint.h>

typedef unsigned short u16;

#define D_MODEL 2048
#define HEADS 16
#define HDIM 128
#define SEQ 2048
#define BATCH 2
#define NROWS (BATCH*SEQ)          // 4096
#define QKV_N (D_MODEL + 2*HDIM)   // 2304

// softmax scale folded into wq/bq at prep: 1/sqrt(128) * log2(e)
#define SC2F 0.12751743f

typedef __attribute__((ext_vector_type(8))) short bf16x8;
typedef __attribute__((ext_vector_type(4))) float f32x4;

__device__ inline u16 f2bf(float f) {
  union { float f; uint32_t u; } v; v.f = f;
  uint32_t r = v.u + 0x7FFFu + ((v.u >> 16) & 1u);
  return (u16)(r >> 16);
}
__device__ inline u16 f2bf_fast(float f) {
  union { float f; uint32_t u; } v; v.f = f;
  return (u16)((v.u + 0x8000u) >> 16);
}

__device__ inline void gload_lds16(const void* g, void* l) {
  __builtin_amdgcn_global_load_lds(
      (const __attribute__((address_space(1))) unsigned int*)g,
      (__attribute__((address_space(3))) unsigned int*)l, 16, 0, 0);
}

// ---------------- fused prep: x cvt + all-weight transpose + bias pack ------
// grid: [0,1024) grid-stride cvt x ; [1024,9728) transpose ; 9728 bias
// wq (and bq) are PRE-SCALED by SC2F so attention scores feed exp2 directly.
__global__ void prep_all(const float* __restrict__ x, u16* __restrict__ xb,
                         const float* __restrict__ wq, const float* __restrict__ wk,
                         const float* __restrict__ wv, const float* __restrict__ wo,
                         u16* __restrict__ wqkvT, u16* __restrict__ woT,
                         const float* __restrict__ bq, const float* __restrict__ bk,
                         const float* __restrict__ bv, float* __restrict__ biasq) {
  const int bid = blockIdx.x, tid = threadIdx.x;
  if (bid < 1024) {
    const float4* xf = (const float4*)x;
    ushort4* xo = (ushort4*)xb;
    int i = bid * 256 + tid;
#pragma unroll
    for (int r = 0; r < 8; r++, i += 262144) {
      float4 f = xf[i];
      ushort4 u;
      u.x = f2bf(f.x); u.y = f2bf(f.y); u.z = f2bf(f.z); u.w = f2bf(f.w);
      xo[i] = u;
    }
  } else if (bid < 9728) {
    __shared__ float t[32][33];
    const int b2 = bid - 1024;
    const int n0v = (b2 % 136) * 32, k0 = (b2 / 136) * 32;
    const float* src; int N, n0, drow; u16* dst; float scl = 1.0f;
    if (n0v < 2048)      { src = wq; N = 2048; n0 = n0v;        dst = wqkvT; drow = n0v; scl = SC2F; }
    else if (n0v < 2176) { src = wk; N = 128;  n0 = n0v - 2048; dst = wqkvT; drow = n0v; }
    else if (n0v < 2304) { src = wv; N = 128;  n0 = n0v - 2176; dst = wqkvT; drow = n0v; }
    else                 { src = wo; N = 2048; n0 = n0v - 2304; dst = woT;   drow = n0v - 2304; }
    const int tx = tid & 31, ty = tid >> 5;
#pragma unroll
    for (int i = 0; i < 4; i++)
      t[ty + 8*i][tx] = src[(size_t)(k0 + ty + 8*i) * N + n0 + tx];
    __syncthreads();
#pragma unroll
    for (int i = 0; i < 4; i++)
      dst[(size_t)(drow + ty + 8*i) * D_MODEL + k0 + tx] = f2bf(t[tx][ty + 8*i] * scl);
  } else {
    for (int i = tid; i < QKV_N; i += 256)
      biasq[i] = (i < D_MODEL) ? bq[i] * SC2F
               : ((i < D_MODEL + HDIM) ? bk[i - D_MODEL] : bv[i - D_MODEL - HDIM]);
  }
}

// ---------------- bf16 GEMM, BK=64, XOR-swizzled LDS, templated BN ----------
// C = A[M,K]*BT[N,K]^T + bias. BM=128, BN = NBT*16; 4 waves, wave tile
// 64 x (NBT*8). Chunk-XOR swizzle depends only on row&7 -> preserved for any
// NBT (all row offsets are multiples of 8/16).
// gemm1: NBT=6 (BN=96) -> 2304/96=24 tilesN, 32x24=768 blocks = UNIFORM 3/CU
//        (fixes the 576-block 2.25/CU ragged tail), DB=false, 28 KB LDS.
// gemm2: NBT=8 (BN=128) -> byte-identical to the proven R6 config, DB=true,
//        512 blocks = uniform 2/CU.
#define BM 128
#define BKK 64

template <bool DB, int MINW, int NBT>
__global__ __launch_bounds__(256, MINW) void gemm_bt(
    const u16* __restrict__ A, const u16* __restrict__ BT,
    const float* __restrict__ bias,
    u16* __restrict__ Cb, float* __restrict__ Cf,
    u16* __restrict__ vT,
    int M, int N, int tilesN, int K) {
  __shared__ __align__(16) u16 sA[DB ? 2 : 1][BM * BKK];
  __shared__ __align__(16) u16 sB[DB ? 2 : 1][NBT * 16 * BKK];
  const int tid = threadIdx.x;
  const int wave = tid >> 6, lane = tid & 63;
  const int bm = blockIdx.x / tilesN, bn = blockIdx.x % tilesN;
  const int m0 = bm * BM, n0 = bn * (NBT * 16);
  const int wm = (wave & 1) * 64, wn = (wave >> 1) * (NBT * 8);
  const int l16 = lane & 15, quad = lane >> 4;

  f32x4 acc[4][NBT / 2] = {};

  // DMA map: op i covers rows i*8 + (lane>>3); global chunk = (lane&7)^(lane>>3)
  const int dRow = lane >> 3;
  const int dCol = ((lane & 7) ^ (lane >> 3)) * 8;

#define GDMA(i, buf)                                                           \
  {                                                                            \
    const int _k0 = (i) * BKK;                                                 \
    _Pragma("unroll") for (int c = 0; c < 4; c++) {                            \
      const int op = wave * 4 + c;                                             \
      const int row = op * 8 + dRow;                                           \
      gload_lds16(&A[(size_t)(m0 + row) * K + _k0 + dCol], &sA[buf][op * 512]);\
    }                                                                          \
    _Pragma("unroll") for (int c = 0; c < NBT / 2; c++) {                      \
      const int op = wave * (NBT / 2) + c;                                     \
      const int row = op * 8 + dRow;                                           \
      gload_lds16(&BT[(size_t)(n0 + row) * K + _k0 + dCol], &sB[buf][op * 512]);\
    }                                                                          \
  }

  const int NI = K / BKK;
  GDMA(0, 0);
  for (int i = 0; i < NI; i++) {
    const int cur = DB ? (i & 1) : 0;
    __syncthreads();                       // drain DMA(i)
    if (DB && i + 1 < NI) GDMA(i + 1, cur ^ 1);
#pragma unroll
    for (int kk2 = 0; kk2 < 2; kk2++) {    // K halves: kk = kk2*32
      bf16x8 af[4], bfr[NBT / 2];
#pragma unroll
      for (int mb = 0; mb < 4; ++mb) {
        const int R = wm + mb * 16 + l16;
        const int s = (kk2 * 4 + quad) ^ (l16 & 7);
        af[mb] = *(const bf16x8*)&sA[cur][R * BKK + s * 8];
      }
#pragma unroll
      for (int nb = 0; nb < NBT / 2; ++nb) {
        const int R = wn + nb * 16 + l16;
        const int s = (kk2 * 4 + quad) ^ (l16 & 7);
        bfr[nb] = *(const bf16x8*)&sB[cur][R * BKK + s * 8];
      }
#pragma unroll
      for (int mb = 0; mb < 4; ++mb)
#pragma unroll
        for (int nb = 0; nb < NBT / 2; ++nb)
          acc[mb][nb] = __builtin_amdgcn_mfma_f32_16x16x32_bf16(af[mb], bfr[nb], acc[mb][nb], 0, 0, 0);
    }
    if (!DB) {
      __syncthreads();                     // all readers done with the buffer
      if (i + 1 < NI) GDMA(i + 1, 0);
    }
  }
#undef GDMA

  // epilogue: C/D layout col=lane&15, row=(lane>>4)*4+r
#pragma unroll
  for (int mb = 0; mb < 4; ++mb) {
#pragma unroll
    for (int nb = 0; nb < NBT / 2; ++nb) {
      const int gn = n0 + wn + nb * 16 + l16;
      const float bb = bias ? bias[gn] : 0.0f;
#pragma unroll
      for (int r = 0; r < 4; ++r) {
        const int gm = m0 + wm + mb * 16 + quad * 4 + r;
        const float v = acc[mb][nb][r] + bb;
        if (Cf) {
          Cf[(size_t)gm * N + gn] = v;
        } else {
          const u16 u = f2bf(v);
          Cb[(size_t)gm * N + gn] = u;
          if (vT && gn >= D_MODEL + HDIM) {
            const int bi = gm >> 11, si = gm & 2047;
            vT[((size_t)bi * HDIM + (gn - D_MODEL - HDIM)) * SEQ + si] = u;
          }
        }
      }
    }
  }
}

// ---------------- flash-style MQA attention (FROZEN: best measured 86.2) ----
// 4 waves x 32 q-rows, sK dbuf + sV single + sP wave-private, 2 barriers/iter,
// no setprio (R1 A/B: -2%). Q pre-scaled at prep (SC2F) -> exp2 direct.
__global__ __launch_bounds__(256) void mqa_attn(
    const u16* __restrict__ qkv, const u16* __restrict__ vT, u16* __restrict__ ctx) {
  __shared__ __align__(16) u16 sK[2][64 * 128];
  __shared__ __align__(16) u16 sV[128 * 64];
  __shared__ __align__(16) u16 sP[4][32 * 64];
  const int tid = threadIdx.x, wave = tid >> 6, lane = tid & 63;
  const int qt = blockIdx.x & 15;
  const int h  = (blockIdx.x >> 4) & 15;
  const int b  = blockIdx.x >> 8;
  const int bS = b * SEQ;
  const int q0 = qt * 128 + wave * 32;
  const int l16 = lane & 15, quad = lane >> 4;
  const int sw = l16 & 7;
  u16* myP = &sP[wave][0];

  bf16x8 qf[2][4];
#pragma unroll
  for (int mb = 0; mb < 2; mb++)
#pragma unroll
    for (int kc = 0; kc < 4; kc++)
      qf[mb][kc] = *(const bf16x8*)&qkv[(size_t)(bS + q0 + mb*16 + l16) * QKV_N
                                        + h*HDIM + kc*32 + quad*8];

  f32x4 o[2][8] = {};
  float lrow[2] = {0.f, 0.f};

  const u16* Kbase = qkv + (size_t)bS * QKV_N + D_MODEL;
  const u16* Vbase = vT + (size_t)b * HDIM * SEQ;

  const int kRowIn = lane >> 4;
  const int kChS   = lane & 15;
  const int vRowIn = lane >> 3;
  const int vChL   = (lane & 7) ^ (lane >> 3);

#define DMA_K(t, dst)                                                          \
  {                                                                            \
    const int _sk = (t) * 64;                                                  \
    _Pragma("unroll") for (int j = 0; j < 4; j++) {                            \
      const int i = wave * 4 + j;                                              \
      const int krow = i * 4 + kRowIn;                                         \
      const int kcl = kChS ^ (krow & 15);                                      \
      gload_lds16(&Kbase[(size_t)(_sk + krow) * QKV_N + kcl * 8],              \
                  &(dst)[i * 512]);                                            \
    }                                                                          \
  }
#define DMA_V(t)                                                               \
  {                                                                            \
    const int _sk = (t) * 64;                                                  \
    _Pragma("unroll") for (int j = 0; j < 4; j++) {                            \
      const int i = wave * 4 + j;                                              \
      const int d = i * 8 + vRowIn;                                            \
      gload_lds16(&Vbase[(size_t)d * SEQ + _sk + vChL * 8], &sV[i * 512]);     \
    }                                                                          \
  }

  DMA_K(0, sK[0]);
  DMA_V(0);
  __syncthreads();

  const int T = SEQ / 64;
  for (int t = 0; t < T; ++t) {
    const int cur = t & 1;
    if (t + 1 < T) DMA_K(t + 1, sK[cur ^ 1]);

    f32x4 sc[2][4];
#pragma unroll
    for (int nb = 0; nb < 4; nb++) {
      bf16x8 kf[4];
#pragma unroll
      for (int kc = 0; kc < 4; kc++)
        kf[kc] = *(const bf16x8*)&sK[cur][(nb*16 + l16) * 128 + (((kc*4 + quad) ^ l16) * 8)];
#pragma unroll
      for (int mb = 0; mb < 2; mb++) {
        f32x4 a = {0.f, 0.f, 0.f, 0.f};
#pragma unroll
        for (int kc = 0; kc < 4; kc++)
          a = __builtin_amdgcn_mfma_f32_16x16x32_bf16(kf[kc], qf[mb][kc], a, 0, 0, 0);
        sc[mb][nb] = a;
      }
    }

#pragma unroll
    for (int mb = 0; mb < 2; mb++)
#pragma unroll
      for (int nb = 0; nb < 4; nb++) {
        float p0 = __builtin_amdgcn_exp2f(sc[mb][nb][0]);
        float p1 = __builtin_amdgcn_exp2f(sc[mb][nb][1]);
        float p2 = __builtin_amdgcn_exp2f(sc[mb][nb][2]);
        float p3 = __builtin_amdgcn_exp2f(sc[mb][nb][3]);
        lrow[mb] += (p0 + p1) + (p2 + p3);
        uint32_t lo = (uint32_t)f2bf_fast(p0) | ((uint32_t)f2bf_fast(p1) << 16);
        uint32_t hi = (uint32_t)f2bf_fast(p2) | ((uint32_t)f2bf_fast(p3) << 16);
        uint2 w; w.x = lo; w.y = hi;
        const int pr = (nb*2 + (quad >> 1)) ^ sw;
        *(uint2*)&myP[(mb*16 + l16) * 64 + pr * 8 + (quad & 1) * 4] = w;
      }

    __syncthreads();

    bf16x8 pf[2][2];
#pragma unroll
    for (int mb = 0; mb < 2; mb++)
#pragma unroll
      for (int kc = 0; kc < 2; kc++)
        pf[mb][kc] = *(const bf16x8*)&myP[(mb*16 + l16) * 64 + (((kc*4 + quad) ^ sw) * 8)];

#pragma unroll
    for (int nb = 0; nb < 8; nb++) {
      bf16x8 vf[2];
#pragma unroll
      for (int kc = 0; kc < 2; kc++)
        vf[kc] = *(const bf16x8*)&sV[(nb*16 + l16) * 64 + (((kc*4 + quad) ^ (l16 & 7)) * 8)];
#pragma unroll
      for (int mb = 0; mb < 2; mb++)
#pragma unroll
        for (int kc = 0; kc < 2; kc++)
          o[mb][nb] = __builtin_amdgcn_mfma_f32_16x16x32_bf16(pf[mb][kc], vf[kc], o[mb][nb], 0, 0, 0);
    }

    __syncthreads();
    if (t + 1 < T) DMA_V(t + 1);
  }

#pragma unroll
  for (int mb = 0; mb < 2; mb++) {
    lrow[mb] += __shfl_xor(lrow[mb], 16, 64);
    lrow[mb] += __shfl_xor(lrow[mb], 32, 64);
  }
  float invl[2][4];
#pragma unroll
  for (int mb = 0; mb < 2; mb++)
#pragma unroll
    for (int r = 0; r < 4; r++)
      invl[mb][r] = 1.0f / __shfl(lrow[mb], quad * 4 + r, 64);

#pragma unroll
  for (int mb = 0; mb < 2; mb++)
#pragma unroll
    for (int nb = 0; nb < 8; nb++)
#pragma unroll
      for (int r = 0; r < 4; r++) {
        const int gq = q0 + mb*16 + quad*4 + r;
        const int gd = h * HDIM + nb*16 + l16;
        ctx[(size_t)(bS + gq) * D_MODEL + gd] = f2bf(o[mb][nb][r] * invl[mb][r]);
      }
}

// ---------------- launch ----------------
extern "C" void kernel_launch(void* const* d_in, const int* in_sizes, int n_in,
                              void* d_out, int out_size, void* d_ws, size_t ws_size,
                              hipStream_t stream) {
  const float* x  = (const float*)d_in[0];
  const float* wq = (const float*)d_in[1];
  const float* bq = (const float*)d_in[2];
  const float* wk = (const float*)d_in[3];
  const float* bk = (const float*)d_in[4];
  const float* wv = (const float*)d_in[5];
  const float* bv = (const float*)d_in[6];
  const float* wo = (const float*)d_in[7];
  const float* bo = (const float*)d_in[8];
  float* out = (float*)d_out;
  char* ws = (char*)d_ws;

  u16*   xb    = (u16*)(ws + 0);          // [4096,2048] bf16
  u16*   wqkvT = (u16*)(ws + 16777216);   // [2304,2048] bf16
  u16*   woT   = (u16*)(ws + 26214400);   // [2048,2048] bf16
  u16*   qkv   = (u16*)(ws + 34603008);   // [4096,2304] bf16
  u16*   vT    = (u16*)(ws + 53477376);   // [2,128,2048] bf16
  u16*   ctx   = (u16*)(ws + 54525952);   // [4096,2048] bf16
  float* biasq = (float*)(ws + 71303168); // [2304] f32

  prep_all<<<9729, 256, 0, stream>>>(x, xb, wq, wk, wv, wo, wqkvT, woT,
                                     bq, bk, bv, biasq);
  // merged QKV projection: BN=96 -> 32x24 = 768 blocks, UNIFORM 3/CU
  gemm_bt<false, 3, 6><<<32 * 24, 256, 0, stream>>>(xb, wqkvT, biasq, qkv, nullptr, vT,
                                                    NROWS, QKV_N, 24, D_MODEL);
  // attention: frozen best config (86.2 µs)
  mqa_attn<<<BATCH * HEADS * (SEQ / 128), 256, 0, stream>>>(qkv, vT, ctx);
  // output projection: BN=128, 512 blocks (2/CU), double-buffered (unchanged)
  gemm_bt<true, 2, 8><<<32 * 16, 256, 0, stream>>>(ctx, woT, bo, nullptr, out, nullptr,
                                                   NROWS, D_MODEL, 16, D_MODEL);
}

// Round 10
// 290.626 us; speedup vs baseline: 1.2002x; 1.0012x over previous
//
#include <hip/hip_runtime.h>
#include <stdint.h>

typedef unsigned short u16;

#define D_MODEL 2048
#define HEADS 16
#define HDIM 128
#define SEQ 2048
#define BATCH 2
#define NROWS (BATCH*SEQ)          // 4096
#define QKV_N (D_MODEL + 2*HDIM)   // 2304

// softmax scale folded into wq/bq at prep: 1/sqrt(128) * log2(e)
#define SC2F 0.12751743f

typedef __attribute__((ext_vector_type(8))) short bf16x8;
typedef __attribute__((ext_vector_type(4))) float f32x4;

__device__ inline u16 f2bf(float f) {
  union { float f; uint32_t u; } v; v.f = f;
  uint32_t r = v.u + 0x7FFFu + ((v.u >> 16) & 1u);
  return (u16)(r >> 16);
}
__device__ inline u16 f2bf_fast(float f) {
  union { float f; uint32_t u; } v; v.f = f;
  return (u16)((v.u + 0x8000u) >> 16);
}

__device__ inline void gload_lds16(const void* g, void* l) {
  __builtin_amdgcn_global_load_lds(
      (const __attribute__((address_space(1))) unsigned int*)g,
      (__attribute__((address_space(3))) unsigned int*)l, 16, 0, 0);
}

// ---------------- fused prep: x cvt + all-weight transpose + bias pack ------
// grid: [0,1024) grid-stride cvt x ; [1024,9728) transpose ; 9728 bias
// wq (and bq) are PRE-SCALED by SC2F so attention scores feed exp2 directly.
__global__ void prep_all(const float* __restrict__ x, u16* __restrict__ xb,
                         const float* __restrict__ wq, const float* __restrict__ wk,
                         const float* __restrict__ wv, const float* __restrict__ wo,
                         u16* __restrict__ wqkvT, u16* __restrict__ woT,
                         const float* __restrict__ bq, const float* __restrict__ bk,
                         const float* __restrict__ bv, float* __restrict__ biasq) {
  const int bid = blockIdx.x, tid = threadIdx.x;
  if (bid < 1024) {
    const float4* xf = (const float4*)x;
    ushort4* xo = (ushort4*)xb;
    int i = bid * 256 + tid;
#pragma unroll
    for (int r = 0; r < 8; r++, i += 262144) {
      float4 f = xf[i];
      ushort4 u;
      u.x = f2bf(f.x); u.y = f2bf(f.y); u.z = f2bf(f.z); u.w = f2bf(f.w);
      xo[i] = u;
    }
  } else if (bid < 9728) {
    __shared__ float t[32][33];
    const int b2 = bid - 1024;
    const int n0v = (b2 % 136) * 32, k0 = (b2 / 136) * 32;
    const float* src; int N, n0, drow; u16* dst; float scl = 1.0f;
    if (n0v < 2048)      { src = wq; N = 2048; n0 = n0v;        dst = wqkvT; drow = n0v; scl = SC2F; }
    else if (n0v < 2176) { src = wk; N = 128;  n0 = n0v - 2048; dst = wqkvT; drow = n0v; }
    else if (n0v < 2304) { src = wv; N = 128;  n0 = n0v - 2176; dst = wqkvT; drow = n0v; }
    else                 { src = wo; N = 2048; n0 = n0v - 2304; dst = woT;   drow = n0v - 2304; }
    const int tx = tid & 31, ty = tid >> 5;
#pragma unroll
    for (int i = 0; i < 4; i++)
      t[ty + 8*i][tx] = src[(size_t)(k0 + ty + 8*i) * N + n0 + tx];
    __syncthreads();
#pragma unroll
    for (int i = 0; i < 4; i++)
      dst[(size_t)(drow + ty + 8*i) * D_MODEL + k0 + tx] = f2bf(t[tx][ty + 8*i] * scl);
  } else {
    for (int i = tid; i < QKV_N; i += 256)
      biasq[i] = (i < D_MODEL) ? bq[i] * SC2F
               : ((i < D_MODEL + HDIM) ? bk[i - D_MODEL] : bv[i - D_MODEL - HDIM]);
  }
}

// ---------------- bf16 GEMM, BK=64, XOR-swizzled LDS, templated BN ----------
// C = A[M,K]*BT[N,K]^T + bias. BM=128, BN = NBT*16; 4 waves, wave tile
// 64 x (NBT*8). Chunk-XOR swizzle depends only on row&7 -> preserved for any
// even NBT.
// gemm1: NBT=6 (BN=96), DB=false -> 768 blocks, uniform 3/CU (R7 proven).
// gemm2: NBT=4 (BN=64), DB=false -> 1024 blocks, uniform 4/CU, 24 KB LDS,
//        MINW=4 (VGPR<=128). R8/R9 experiment: does 4-block co-residency hide
//        the per-iter vmcnt(0) drain that the budget math says is the wall?
#define BM 128
#define BKK 64

template <bool DB, int MINW, int NBT>
__global__ __launch_bounds__(256, MINW) void gemm_bt(
    const u16* __restrict__ A, const u16* __restrict__ BT,
    const float* __restrict__ bias,
    u16* __restrict__ Cb, float* __restrict__ Cf,
    u16* __restrict__ vT,
    int M, int N, int tilesN, int K) {
  __shared__ __align__(16) u16 sA[DB ? 2 : 1][BM * BKK];
  __shared__ __align__(16) u16 sB[DB ? 2 : 1][NBT * 16 * BKK];
  const int tid = threadIdx.x;
  const int wave = tid >> 6, lane = tid & 63;
  const int bm = blockIdx.x / tilesN, bn = blockIdx.x % tilesN;
  const int m0 = bm * BM, n0 = bn * (NBT * 16);
  const int wm = (wave & 1) * 64, wn = (wave >> 1) * (NBT * 8);
  const int l16 = lane & 15, quad = lane >> 4;

  f32x4 acc[4][NBT / 2] = {};

  // DMA map: op i covers rows i*8 + (lane>>3); global chunk = (lane&7)^(lane>>3)
  const int dRow = lane >> 3;
  const int dCol = ((lane & 7) ^ (lane >> 3)) * 8;

#define GDMA(i, buf)                                                           \
  {                                                                            \
    const int _k0 = (i) * BKK;                                                 \
    _Pragma("unroll") for (int c = 0; c < 4; c++) {                            \
      const int op = wave * 4 + c;                                             \
      const int row = op * 8 + dRow;                                           \
      gload_lds16(&A[(size_t)(m0 + row) * K + _k0 + dCol], &sA[buf][op * 512]);\
    }                                                                          \
    _Pragma("unroll") for (int c = 0; c < NBT / 2; c++) {                      \
      const int op = wave * (NBT / 2) + c;                                     \
      const int row = op * 8 + dRow;                                           \
      gload_lds16(&BT[(size_t)(n0 + row) * K + _k0 + dCol], &sB[buf][op * 512]);\
    }                                                                          \
  }

  const int NI = K / BKK;
  GDMA(0, 0);
  for (int i = 0; i < NI; i++) {
    const int cur = DB ? (i & 1) : 0;
    __syncthreads();                       // drain DMA(i)
    if (DB && i + 1 < NI) GDMA(i + 1, cur ^ 1);
#pragma unroll
    for (int kk2 = 0; kk2 < 2; kk2++) {    // K halves: kk = kk2*32
      bf16x8 af[4], bfr[NBT / 2];
#pragma unroll
      for (int mb = 0; mb < 4; ++mb) {
        const int R = wm + mb * 16 + l16;
        const int s = (kk2 * 4 + quad) ^ (l16 & 7);
        af[mb] = *(const bf16x8*)&sA[cur][R * BKK + s * 8];
      }
#pragma unroll
      for (int nb = 0; nb < NBT / 2; ++nb) {
        const int R = wn + nb * 16 + l16;
        const int s = (kk2 * 4 + quad) ^ (l16 & 7);
        bfr[nb] = *(const bf16x8*)&sB[cur][R * BKK + s * 8];
      }
#pragma unroll
      for (int mb = 0; mb < 4; ++mb)
#pragma unroll
        for (int nb = 0; nb < NBT / 2; ++nb)
          acc[mb][nb] = __builtin_amdgcn_mfma_f32_16x16x32_bf16(af[mb], bfr[nb], acc[mb][nb], 0, 0, 0);
    }
    if (!DB) {
      __syncthreads();                     // all readers done with the buffer
      if (i + 1 < NI) GDMA(i + 1, 0);
    }
  }
#undef GDMA

  // epilogue: C/D layout col=lane&15, row=(lane>>4)*4+r
#pragma unroll
  for (int mb = 0; mb < 4; ++mb) {
#pragma unroll
    for (int nb = 0; nb < NBT / 2; ++nb) {
      const int gn = n0 + wn + nb * 16 + l16;
      const float bb = bias ? bias[gn] : 0.0f;
#pragma unroll
      for (int r = 0; r < 4; ++r) {
        const int gm = m0 + wm + mb * 16 + quad * 4 + r;
        const float v = acc[mb][nb][r] + bb;
        if (Cf) {
          Cf[(size_t)gm * N + gn] = v;
        } else {
          const u16 u = f2bf(v);
          Cb[(size_t)gm * N + gn] = u;
          if (vT && gn >= D_MODEL + HDIM) {
            const int bi = gm >> 11, si = gm & 2047;
            vT[((size_t)bi * HDIM + (gn - D_MODEL - HDIM)) * SEQ + si] = u;
          }
        }
      }
    }
  }
}

// ---------------- flash-style MQA attention (FROZEN: best measured 86.2) ----
// 4 waves x 32 q-rows, sK dbuf + sV single + sP wave-private, 2 barriers/iter,
// no setprio (R1 A/B: -2%). Q pre-scaled at prep (SC2F) -> exp2 direct.
__global__ __launch_bounds__(256) void mqa_attn(
    const u16* __restrict__ qkv, const u16* __restrict__ vT, u16* __restrict__ ctx) {
  __shared__ __align__(16) u16 sK[2][64 * 128];
  __shared__ __align__(16) u16 sV[128 * 64];
  __shared__ __align__(16) u16 sP[4][32 * 64];
  const int tid = threadIdx.x, wave = tid >> 6, lane = tid & 63;
  const int qt = blockIdx.x & 15;
  const int h  = (blockIdx.x >> 4) & 15;
  const int b  = blockIdx.x >> 8;
  const int bS = b * SEQ;
  const int q0 = qt * 128 + wave * 32;
  const int l16 = lane & 15, quad = lane >> 4;
  const int sw = l16 & 7;
  u16* myP = &sP[wave][0];

  bf16x8 qf[2][4];
#pragma unroll
  for (int mb = 0; mb < 2; mb++)
#pragma unroll
    for (int kc = 0; kc < 4; kc++)
      qf[mb][kc] = *(const bf16x8*)&qkv[(size_t)(bS + q0 + mb*16 + l16) * QKV_N
                                        + h*HDIM + kc*32 + quad*8];

  f32x4 o[2][8] = {};
  float lrow[2] = {0.f, 0.f};

  const u16* Kbase = qkv + (size_t)bS * QKV_N + D_MODEL;
  const u16* Vbase = vT + (size_t)b * HDIM * SEQ;

  const int kRowIn = lane >> 4;
  const int kChS   = lane & 15;
  const int vRowIn = lane >> 3;
  const int vChL   = (lane & 7) ^ (lane >> 3);

#define DMA_K(t, dst)                                                          \
  {                                                                            \
    const int _sk = (t) * 64;                                                  \
    _Pragma("unroll") for (int j = 0; j < 4; j++) {                            \
      const int i = wave * 4 + j;                                              \
      const int krow = i * 4 + kRowIn;                                         \
      const int kcl = kChS ^ (krow & 15);                                      \
      gload_lds16(&Kbase[(size_t)(_sk + krow) * QKV_N + kcl * 8],              \
                  &(dst)[i * 512]);                                            \
    }                                                                          \
  }
#define DMA_V(t)                                                               \
  {                                                                            \
    const int _sk = (t) * 64;                                                  \
    _Pragma("unroll") for (int j = 0; j < 4; j++) {                            \
      const int i = wave * 4 + j;                                              \
      const int d = i * 8 + vRowIn;                                            \
      gload_lds16(&Vbase[(size_t)d * SEQ + _sk + vChL * 8], &sV[i * 512]);     \
    }                                                                          \
  }

  DMA_K(0, sK[0]);
  DMA_V(0);
  __syncthreads();

  const int T = SEQ / 64;
  for (int t = 0; t < T; ++t) {
    const int cur = t & 1;
    if (t + 1 < T) DMA_K(t + 1, sK[cur ^ 1]);

    f32x4 sc[2][4];
#pragma unroll
    for (int nb = 0; nb < 4; nb++) {
      bf16x8 kf[4];
#pragma unroll
      for (int kc = 0; kc < 4; kc++)
        kf[kc] = *(const bf16x8*)&sK[cur][(nb*16 + l16) * 128 + (((kc*4 + quad) ^ l16) * 8)];
#pragma unroll
      for (int mb = 0; mb < 2; mb++) {
        f32x4 a = {0.f, 0.f, 0.f, 0.f};
#pragma unroll
        for (int kc = 0; kc < 4; kc++)
          a = __builtin_amdgcn_mfma_f32_16x16x32_bf16(kf[kc], qf[mb][kc], a, 0, 0, 0);
        sc[mb][nb] = a;
      }
    }

#pragma unroll
    for (int mb = 0; mb < 2; mb++)
#pragma unroll
      for (int nb = 0; nb < 4; nb++) {
        float p0 = __builtin_amdgcn_exp2f(sc[mb][nb][0]);
        float p1 = __builtin_amdgcn_exp2f(sc[mb][nb][1]);
        float p2 = __builtin_amdgcn_exp2f(sc[mb][nb][2]);
        float p3 = __builtin_amdgcn_exp2f(sc[mb][nb][3]);
        lrow[mb] += (p0 + p1) + (p2 + p3);
        uint32_t lo = (uint32_t)f2bf_fast(p0) | ((uint32_t)f2bf_fast(p1) << 16);
        uint32_t hi = (uint32_t)f2bf_fast(p2) | ((uint32_t)f2bf_fast(p3) << 16);
        uint2 w; w.x = lo; w.y = hi;
        const int pr = (nb*2 + (quad >> 1)) ^ sw;
        *(uint2*)&myP[(mb*16 + l16) * 64 + pr * 8 + (quad & 1) * 4] = w;
      }

    __syncthreads();

    bf16x8 pf[2][2];
#pragma unroll
    for (int mb = 0; mb < 2; mb++)
#pragma unroll
      for (int kc = 0; kc < 2; kc++)
        pf[mb][kc] = *(const bf16x8*)&myP[(mb*16 + l16) * 64 + (((kc*4 + quad) ^ sw) * 8)];

#pragma unroll
    for (int nb = 0; nb < 8; nb++) {
      bf16x8 vf[2];
#pragma unroll
      for (int kc = 0; kc < 2; kc++)
        vf[kc] = *(const bf16x8*)&sV[(nb*16 + l16) * 64 + (((kc*4 + quad) ^ (l16 & 7)) * 8)];
#pragma unroll
      for (int mb = 0; mb < 2; mb++)
#pragma unroll
        for (int kc = 0; kc < 2; kc++)
          o[mb][nb] = __builtin_amdgcn_mfma_f32_16x16x32_bf16(pf[mb][kc], vf[kc], o[mb][nb], 0, 0, 0);
    }

    __syncthreads();
    if (t + 1 < T) DMA_V(t + 1);
  }

#pragma unroll
  for (int mb = 0; mb < 2; mb++) {
    lrow[mb] += __shfl_xor(lrow[mb], 16, 64);
    lrow[mb] += __shfl_xor(lrow[mb], 32, 64);
  }
  float invl[2][4];
#pragma unroll
  for (int mb = 0; mb < 2; mb++)
#pragma unroll
    for (int r = 0; r < 4; r++)
      invl[mb][r] = 1.0f / __shfl(lrow[mb], quad * 4 + r, 64);

#pragma unroll
  for (int mb = 0; mb < 2; mb++)
#pragma unroll
    for (int nb = 0; nb < 8; nb++)
#pragma unroll
      for (int r = 0; r < 4; r++) {
        const int gq = q0 + mb*16 + quad*4 + r;
        const int gd = h * HDIM + nb*16 + l16;
        ctx[(size_t)(bS + gq) * D_MODEL + gd] = f2bf(o[mb][nb][r] * invl[mb][r]);
      }
}

// ---------------- launch ----------------
extern "C" void kernel_launch(void* const* d_in, const int* in_sizes, int n_in,
                              void* d_out, int out_size, void* d_ws, size_t ws_size,
                              hipStream_t stream) {
  const float* x  = (const float*)d_in[0];
  const float* wq = (const float*)d_in[1];
  const float* bq = (const float*)d_in[2];
  const float* wk = (const float*)d_in[3];
  const float* bk = (const float*)d_in[4];
  const float* wv = (const float*)d_in[5];
  const float* bv = (const float*)d_in[6];
  const float* wo = (const float*)d_in[7];
  const float* bo = (const float*)d_in[8];
  float* out = (float*)d_out;
  char* ws = (char*)d_ws;

  u16*   xb    = (u16*)(ws + 0);          // [4096,2048] bf16
  u16*   wqkvT = (u16*)(ws + 16777216);   // [2304,2048] bf16
  u16*   woT   = (u16*)(ws + 26214400);   // [2048,2048] bf16
  u16*   qkv   = (u16*)(ws + 34603008);   // [4096,2304] bf16
  u16*   vT    = (u16*)(ws + 53477376);   // [2,128,2048] bf16
  u16*   ctx   = (u16*)(ws + 54525952);   // [4096,2048] bf16
  float* biasq = (float*)(ws + 71303168); // [2304] f32

  prep_all<<<9729, 256, 0, stream>>>(x, xb, wq, wk, wv, wo, wqkvT, woT,
                                     bq, bk, bv, biasq);
  // merged QKV projection: BN=96 -> 768 blocks, uniform 3/CU (R7 proven)
  gemm_bt<false, 3, 6><<<32 * 24, 256, 0, stream>>>(xb, wqkvT, biasq, qkv, nullptr, vT,
                                                    NROWS, QKV_N, 24, D_MODEL);
  // attention: frozen best config (86.2 µs)
  mqa_attn<<<BATCH * HEADS * (SEQ / 128), 256, 0, stream>>>(qkv, vT, ctx);
  // output projection R9 (= R8 resubmit): BN=64 -> 1024 blocks, uniform 4/CU
  gemm_bt<false, 4, 4><<<32 * 32, 256, 0, stream>>>(ctx, woT, bo, nullptr, out, nullptr,
                                                    NROWS, D_MODEL, 32, D_MODEL);
}

// Round 11
// 290.410 us; speedup vs baseline: 1.2011x; 1.0007x over previous
//
#include <hip/hip_runtime.h>
#include <stdint.h>

typedef unsigned short u16;

#define D_MODEL 2048
#define HEADS 16
#define HDIM 128
#define SEQ 2048
#define BATCH 2
#define NROWS (BATCH*SEQ)          // 4096
#define QKV_N (D_MODEL + 2*HDIM)   // 2304

// softmax scale folded into wq/bq at prep: 1/sqrt(128) * log2(e)
#define SC2F 0.12751743f

typedef __attribute__((ext_vector_type(8))) short bf16x8;
typedef __attribute__((ext_vector_type(4))) float f32x4;

__device__ inline u16 f2bf(float f) {
  union { float f; uint32_t u; } v; v.f = f;
  uint32_t r = v.u + 0x7FFFu + ((v.u >> 16) & 1u);
  return (u16)(r >> 16);
}
__device__ inline u16 f2bf_fast(float f) {
  union { float f; uint32_t u; } v; v.f = f;
  return (u16)((v.u + 0x8000u) >> 16);
}

__device__ inline void gload_lds16(const void* g, void* l) {
  __builtin_amdgcn_global_load_lds(
      (const __attribute__((address_space(1))) unsigned int*)g,
      (__attribute__((address_space(3))) unsigned int*)l, 16, 0, 0);
}

// ---------------- fused prep: x cvt + all-weight transpose + bias pack ------
// grid: [0,1024) grid-stride cvt x ; [1024,9728) transpose ; 9728 bias
// wq (and bq) are PRE-SCALED by SC2F so attention scores feed exp2 directly.
__global__ void prep_all(const float* __restrict__ x, u16* __restrict__ xb,
                         const float* __restrict__ wq, const float* __restrict__ wk,
                         const float* __restrict__ wv, const float* __restrict__ wo,
                         u16* __restrict__ wqkvT, u16* __restrict__ woT,
                         const float* __restrict__ bq, const float* __restrict__ bk,
                         const float* __restrict__ bv, float* __restrict__ biasq) {
  const int bid = blockIdx.x, tid = threadIdx.x;
  if (bid < 1024) {
    const float4* xf = (const float4*)x;
    ushort4* xo = (ushort4*)xb;
    int i = bid * 256 + tid;
#pragma unroll
    for (int r = 0; r < 8; r++, i += 262144) {
      float4 f = xf[i];
      ushort4 u;
      u.x = f2bf(f.x); u.y = f2bf(f.y); u.z = f2bf(f.z); u.w = f2bf(f.w);
      xo[i] = u;
    }
  } else if (bid < 9728) {
    __shared__ float t[32][33];
    const int b2 = bid - 1024;
    const int n0v = (b2 % 136) * 32, k0 = (b2 / 136) * 32;
    const float* src; int N, n0, drow; u16* dst; float scl = 1.0f;
    if (n0v < 2048)      { src = wq; N = 2048; n0 = n0v;        dst = wqkvT; drow = n0v; scl = SC2F; }
    else if (n0v < 2176) { src = wk; N = 128;  n0 = n0v - 2048; dst = wqkvT; drow = n0v; }
    else if (n0v < 2304) { src = wv; N = 128;  n0 = n0v - 2176; dst = wqkvT; drow = n0v; }
    else                 { src = wo; N = 2048; n0 = n0v - 2304; dst = woT;   drow = n0v - 2304; }
    const int tx = tid & 31, ty = tid >> 5;
#pragma unroll
    for (int i = 0; i < 4; i++)
      t[ty + 8*i][tx] = src[(size_t)(k0 + ty + 8*i) * N + n0 + tx];
    __syncthreads();
#pragma unroll
    for (int i = 0; i < 4; i++)
      dst[(size_t)(drow + ty + 8*i) * D_MODEL + k0 + tx] = f2bf(t[tx][ty + 8*i] * scl);
  } else {
    for (int i = tid; i < QKV_N; i += 256)
      biasq[i] = (i < D_MODEL) ? bq[i] * SC2F
               : ((i < D_MODEL + HDIM) ? bk[i - D_MODEL] : bv[i - D_MODEL - HDIM]);
  }
}

// ---------------- bf16 GEMM, BK=64, XOR-swizzled LDS, templated BN ----------
// C = A[M,K]*BT[N,K]^T + bias. BM=128, BN = NBT*16; 4 waves, wave tile
// 64 x (NBT*8).
// R10: bijective XCD-chunked blockIdx remap (T1, m157/m204). Default
// round-robin puts blocks of ALL bm rows on every XCD -> each XCD's L2
// fetches the whole A (16.8 MB) + whole B => ~200 MB HBM/gemm. Chunked:
// XCD x gets a contiguous bm-range -> per-XCD fetch ~10 MB, total ~85 MB.
// Requires nwg % 8 == 0: gemm1 768 ✓, gemm2 1024 ✓.
#define BM 128
#define BKK 64
#define NXCD 8

template <bool DB, int MINW, int NBT>
__global__ __launch_bounds__(256, MINW) void gemm_bt(
    const u16* __restrict__ A, const u16* __restrict__ BT,
    const float* __restrict__ bias,
    u16* __restrict__ Cb, float* __restrict__ Cf,
    u16* __restrict__ vT,
    int M, int N, int tilesN, int K) {
  __shared__ __align__(16) u16 sA[DB ? 2 : 1][BM * BKK];
  __shared__ __align__(16) u16 sB[DB ? 2 : 1][NBT * 16 * BKK];
  const int tid = threadIdx.x;
  const int wave = tid >> 6, lane = tid & 63;
  // XCD-chunk remap: hardware round-robins original bid across XCDs;
  // remapped id gives each XCD a contiguous run of (bm,bn) tiles.
  const int nwg = gridDim.x;
  const int cpx = nwg / NXCD;                       // nwg % 8 == 0 required
  const int rb  = (blockIdx.x % NXCD) * cpx + blockIdx.x / NXCD;
  const int bm = rb / tilesN, bn = rb % tilesN;
  const int m0 = bm * BM, n0 = bn * (NBT * 16);
  const int wm = (wave & 1) * 64, wn = (wave >> 1) * (NBT * 8);
  const int l16 = lane & 15, quad = lane >> 4;

  f32x4 acc[4][NBT / 2] = {};

  // DMA map: op i covers rows i*8 + (lane>>3); global chunk = (lane&7)^(lane>>3)
  const int dRow = lane >> 3;
  const int dCol = ((lane & 7) ^ (lane >> 3)) * 8;

#define GDMA(i, buf)                                                           \
  {                                                                            \
    const int _k0 = (i) * BKK;                                                 \
    _Pragma("unroll") for (int c = 0; c < 4; c++) {                            \
      const int op = wave * 4 + c;                                             \
      const int row = op * 8 + dRow;                                           \
      gload_lds16(&A[(size_t)(m0 + row) * K + _k0 + dCol], &sA[buf][op * 512]);\
    }                                                                          \
    _Pragma("unroll") for (int c = 0; c < NBT / 2; c++) {                      \
      const int op = wave * (NBT / 2) + c;                                     \
      const int row = op * 8 + dRow;                                           \
      gload_lds16(&BT[(size_t)(n0 + row) * K + _k0 + dCol], &sB[buf][op * 512]);\
    }                                                                          \
  }

  const int NI = K / BKK;
  GDMA(0, 0);
  for (int i = 0; i < NI; i++) {
    const int cur = DB ? (i & 1) : 0;
    __syncthreads();                       // drain DMA(i)
    if (DB && i + 1 < NI) GDMA(i + 1, cur ^ 1);
#pragma unroll
    for (int kk2 = 0; kk2 < 2; kk2++) {    // K halves: kk = kk2*32
      bf16x8 af[4], bfr[NBT / 2];
#pragma unroll
      for (int mb = 0; mb < 4; ++mb) {
        const int R = wm + mb * 16 + l16;
        const int s = (kk2 * 4 + quad) ^ (l16 & 7);
        af[mb] = *(const bf16x8*)&sA[cur][R * BKK + s * 8];
      }
#pragma unroll
      for (int nb = 0; nb < NBT / 2; ++nb) {
        const int R = wn + nb * 16 + l16;
        const int s = (kk2 * 4 + quad) ^ (l16 & 7);
        bfr[nb] = *(const bf16x8*)&sB[cur][R * BKK + s * 8];
      }
#pragma unroll
      for (int mb = 0; mb < 4; ++mb)
#pragma unroll
        for (int nb = 0; nb < NBT / 2; ++nb)
          acc[mb][nb] = __builtin_amdgcn_mfma_f32_16x16x32_bf16(af[mb], bfr[nb], acc[mb][nb], 0, 0, 0);
    }
    if (!DB) {
      __syncthreads();                     // all readers done with the buffer
      if (i + 1 < NI) GDMA(i + 1, 0);
    }
  }
#undef GDMA

  // epilogue: C/D layout col=lane&15, row=(lane>>4)*4+r
#pragma unroll
  for (int mb = 0; mb < 4; ++mb) {
#pragma unroll
    for (int nb = 0; nb < NBT / 2; ++nb) {
      const int gn = n0 + wn + nb * 16 + l16;
      const float bb = bias ? bias[gn] : 0.0f;
#pragma unroll
      for (int r = 0; r < 4; ++r) {
        const int gm = m0 + wm + mb * 16 + quad * 4 + r;
        const float v = acc[mb][nb][r] + bb;
        if (Cf) {
          Cf[(size_t)gm * N + gn] = v;
        } else {
          const u16 u = f2bf(v);
          Cb[(size_t)gm * N + gn] = u;
          if (vT && gn >= D_MODEL + HDIM) {
            const int bi = gm >> 11, si = gm & 2047;
            vT[((size_t)bi * HDIM + (gn - D_MODEL - HDIM)) * SEQ + si] = u;
          }
        }
      }
    }
  }
}

// ---------------- flash-style MQA attention (FROZEN: best measured 86.2) ----
// 4 waves x 32 q-rows, sK dbuf + sV single + sP wave-private, 2 barriers/iter,
// no setprio (R1 A/B: -2%). Q pre-scaled at prep (SC2F) -> exp2 direct.
// No XCD swizzle: FETCH_SIZE = 16.5 MB ~= one Q read; K/V already L2-cached.
__global__ __launch_bounds__(256) void mqa_attn(
    const u16* __restrict__ qkv, const u16* __restrict__ vT, u16* __restrict__ ctx) {
  __shared__ __align__(16) u16 sK[2][64 * 128];
  __shared__ __align__(16) u16 sV[128 * 64];
  __shared__ __align__(16) u16 sP[4][32 * 64];
  const int tid = threadIdx.x, wave = tid >> 6, lane = tid & 63;
  const int qt = blockIdx.x & 15;
  const int h  = (blockIdx.x >> 4) & 15;
  const int b  = blockIdx.x >> 8;
  const int bS = b * SEQ;
  const int q0 = qt * 128 + wave * 32;
  const int l16 = lane & 15, quad = lane >> 4;
  const int sw = l16 & 7;
  u16* myP = &sP[wave][0];

  bf16x8 qf[2][4];
#pragma unroll
  for (int mb = 0; mb < 2; mb++)
#pragma unroll
    for (int kc = 0; kc < 4; kc++)
      qf[mb][kc] = *(const bf16x8*)&qkv[(size_t)(bS + q0 + mb*16 + l16) * QKV_N
                                        + h*HDIM + kc*32 + quad*8];

  f32x4 o[2][8] = {};
  float lrow[2] = {0.f, 0.f};

  const u16* Kbase = qkv + (size_t)bS * QKV_N + D_MODEL;
  const u16* Vbase = vT + (size_t)b * HDIM * SEQ;

  const int kRowIn = lane >> 4;
  const int kChS   = lane & 15;
  const int vRowIn = lane >> 3;
  const int vChL   = (lane & 7) ^ (lane >> 3);

#define DMA_K(t, dst)                                                          \
  {                                                                            \
    const int _sk = (t) * 64;                                                  \
    _Pragma("unroll") for (int j = 0; j < 4; j++) {                            \
      const int i = wave * 4 + j;                                              \
      const int krow = i * 4 + kRowIn;                                         \
      const int kcl = kChS ^ (krow & 15);                                      \
      gload_lds16(&Kbase[(size_t)(_sk + krow) * QKV_N + kcl * 8],              \
                  &(dst)[i * 512]);                                            \
    }                                                                          \
  }
#define DMA_V(t)                                                               \
  {                                                                            \
    const int _sk = (t) * 64;                                                  \
    _Pragma("unroll") for (int j = 0; j < 4; j++) {                            \
      const int i = wave * 4 + j;                                              \
      const int d = i * 8 + vRowIn;                                            \
      gload_lds16(&Vbase[(size_t)d * SEQ + _sk + vChL * 8], &sV[i * 512]);     \
    }                                                                          \
  }

  DMA_K(0, sK[0]);
  DMA_V(0);
  __syncthreads();

  const int T = SEQ / 64;
  for (int t = 0; t < T; ++t) {
    const int cur = t & 1;
    if (t + 1 < T) DMA_K(t + 1, sK[cur ^ 1]);

    f32x4 sc[2][4];
#pragma unroll
    for (int nb = 0; nb < 4; nb++) {
      bf16x8 kf[4];
#pragma unroll
      for (int kc = 0; kc < 4; kc++)
        kf[kc] = *(const bf16x8*)&sK[cur][(nb*16 + l16) * 128 + (((kc*4 + quad) ^ l16) * 8)];
#pragma unroll
      for (int mb = 0; mb < 2; mb++) {
        f32x4 a = {0.f, 0.f, 0.f, 0.f};
#pragma unroll
        for (int kc = 0; kc < 4; kc++)
          a = __builtin_amdgcn_mfma_f32_16x16x32_bf16(kf[kc], qf[mb][kc], a, 0, 0, 0);
        sc[mb][nb] = a;
      }
    }

#pragma unroll
    for (int mb = 0; mb < 2; mb++)
#pragma unroll
      for (int nb = 0; nb < 4; nb++) {
        float p0 = __builtin_amdgcn_exp2f(sc[mb][nb][0]);
        float p1 = __builtin_amdgcn_exp2f(sc[mb][nb][1]);
        float p2 = __builtin_amdgcn_exp2f(sc[mb][nb][2]);
        float p3 = __builtin_amdgcn_exp2f(sc[mb][nb][3]);
        lrow[mb] += (p0 + p1) + (p2 + p3);
        uint32_t lo = (uint32_t)f2bf_fast(p0) | ((uint32_t)f2bf_fast(p1) << 16);
        uint32_t hi = (uint32_t)f2bf_fast(p2) | ((uint32_t)f2bf_fast(p3) << 16);
        uint2 w; w.x = lo; w.y = hi;
        const int pr = (nb*2 + (quad >> 1)) ^ sw;
        *(uint2*)&myP[(mb*16 + l16) * 64 + pr * 8 + (quad & 1) * 4] = w;
      }

    __syncthreads();

    bf16x8 pf[2][2];
#pragma unroll
    for (int mb = 0; mb < 2; mb++)
#pragma unroll
      for (int kc = 0; kc < 2; kc++)
        pf[mb][kc] = *(const bf16x8*)&myP[(mb*16 + l16) * 64 + (((kc*4 + quad) ^ sw) * 8)];

#pragma unroll
    for (int nb = 0; nb < 8; nb++) {
      bf16x8 vf[2];
#pragma unroll
      for (int kc = 0; kc < 2; kc++)
        vf[kc] = *(const bf16x8*)&sV[(nb*16 + l16) * 64 + (((kc*4 + quad) ^ (l16 & 7)) * 8)];
#pragma unroll
      for (int mb = 0; mb < 2; mb++)
#pragma unroll
        for (int kc = 0; kc < 2; kc++)
          o[mb][nb] = __builtin_amdgcn_mfma_f32_16x16x32_bf16(pf[mb][kc], vf[kc], o[mb][nb], 0, 0, 0);
    }

    __syncthreads();
    if (t + 1 < T) DMA_V(t + 1);
  }

#pragma unroll
  for (int mb = 0; mb < 2; mb++) {
    lrow[mb] += __shfl_xor(lrow[mb], 16, 64);
    lrow[mb] += __shfl_xor(lrow[mb], 32, 64);
  }
  float invl[2][4];
#pragma unroll
  for (int mb = 0; mb < 2; mb++)
#pragma unroll
    for (int r = 0; r < 4; r++)
      invl[mb][r] = 1.0f / __shfl(lrow[mb], quad * 4 + r, 64);

#pragma unroll
  for (int mb = 0; mb < 2; mb++)
#pragma unroll
    for (int nb = 0; nb < 8; nb++)
#pragma unroll
      for (int r = 0; r < 4; r++) {
        const int gq = q0 + mb*16 + quad*4 + r;
        const int gd = h * HDIM + nb*16 + l16;
        ctx[(size_t)(bS + gq) * D_MODEL + gd] = f2bf(o[mb][nb][r] * invl[mb][r]);
      }
}

// ---------------- launch ----------------
extern "C" void kernel_launch(void* const* d_in, const int* in_sizes, int n_in,
                              void* d_out, int out_size, void* d_ws, size_t ws_size,
                              hipStream_t stream) {
  const float* x  = (const float*)d_in[0];
  const float* wq = (const float*)d_in[1];
  const float* bq = (const float*)d_in[2];
  const float* wk = (const float*)d_in[3];
  const float* bk = (const float*)d_in[4];
  const float* wv = (const float*)d_in[5];
  const float* bv = (const float*)d_in[6];
  const float* wo = (const float*)d_in[7];
  const float* bo = (const float*)d_in[8];
  float* out = (float*)d_out;
  char* ws = (char*)d_ws;

  u16*   xb    = (u16*)(ws + 0);          // [4096,2048] bf16
  u16*   wqkvT = (u16*)(ws + 16777216);   // [2304,2048] bf16
  u16*   woT   = (u16*)(ws + 26214400);   // [2048,2048] bf16
  u16*   qkv   = (u16*)(ws + 34603008);   // [4096,2304] bf16
  u16*   vT    = (u16*)(ws + 53477376);   // [2,128,2048] bf16
  u16*   ctx   = (u16*)(ws + 54525952);   // [4096,2048] bf16
  float* biasq = (float*)(ws + 71303168); // [2304] f32

  prep_all<<<9729, 256, 0, stream>>>(x, xb, wq, wk, wv, wo, wqkvT, woT,
                                     bq, bk, bv, biasq);
  // merged QKV projection: BN=96 -> 768 blocks (3/CU), XCD-chunked
  gemm_bt<false, 3, 6><<<32 * 24, 256, 0, stream>>>(xb, wqkvT, biasq, qkv, nullptr, vT,
                                                    NROWS, QKV_N, 24, D_MODEL);
  // attention: frozen best config (86.2 µs)
  mqa_attn<<<BATCH * HEADS * (SEQ / 128), 256, 0, stream>>>(qkv, vT, ctx);
  // output projection: BN=64 -> 1024 blocks (4/CU), XCD-chunked
  gemm_bt<false, 4, 4><<<32 * 32, 256, 0, stream>>>(ctx, woT, bo, nullptr, out, nullptr,
                                                    NROWS, D_MODEL, 32, D_MODEL);
}